// Round 1
// baseline (7514.322 us; speedup 1.0000x reference)
//
#include <hip/hip_runtime.h>
#include <math.h>

#define TOKENS 112896
#define C      384
#define NQKV   1152
#define NFC    1536
#define HEADS  6
#define HD     64
#define WIN    14
#define L      196
#define NWS    24
#define SCALEF 0.125f

// ---------------------------------------------------------------- LayerNorm
// One block per token, 128 threads, 3 elems/thread. PERMUTE writes rows in
// window-partitioned order: token (h,w) -> row ((h/14*24 + w/14)*196 + (h%14)*14 + w%14)
template<bool PERMUTE>
__global__ __launch_bounds__(128) void ln_kernel(const float* __restrict__ x,
    const float* __restrict__ w, const float* __restrict__ b,
    float* __restrict__ out)
{
  const int t = blockIdx.x;
  const int tid = threadIdx.x;
  const float* xr = x + (size_t)t * C;
  float v0 = xr[tid], v1 = xr[tid + 128], v2 = xr[tid + 256];
  float s  = v0 + v1 + v2;
  float ss = v0 * v0 + v1 * v1 + v2 * v2;
#pragma unroll
  for (int off = 32; off > 0; off >>= 1) {
    s  += __shfl_down(s, off);
    ss += __shfl_down(ss, off);
  }
  __shared__ float red[4];
  if ((tid & 63) == 0) { red[(tid >> 6) * 2 + 0] = s; red[(tid >> 6) * 2 + 1] = ss; }
  __syncthreads();
  float S  = red[0] + red[2];
  float SS = red[1] + red[3];
  float mean = S * (1.0f / C);
  float var  = SS * (1.0f / C) - mean * mean;
  float rstd = rsqrtf(var + 1e-5f);
  size_t orow;
  if (PERMUTE) {
    int h_ = t / 336, w_ = t % 336;
    int wh = h_ / WIN, ih = h_ % WIN;
    int ww = w_ / WIN, iw = w_ % WIN;
    orow = (size_t)((wh * NWS + ww) * L + ih * WIN + iw);
  } else {
    orow = (size_t)t;
  }
  float* op = out + orow * C;
  op[tid]       = (v0 - mean) * rstd * w[tid]       + b[tid];
  op[tid + 128] = (v1 - mean) * rstd * w[tid + 128] + b[tid + 128];
  op[tid + 256] = (v2 - mean) * rstd * w[tid + 256] + b[tid + 256];
}

// ---------------------------------------------------------------- GEMM
__device__ __forceinline__ int win_to_tok(int r) {
  int n = r / L, l = r % L;
  int wh = n / NWS, ww = n % NWS;
  int ih = l / WIN, iw = l % WIN;
  return (wh * WIN + ih) * 336 + ww * WIN + iw;
}

__device__ __forceinline__ float gelu_f(float x) {
  return 0.5f * x * (1.0f + erff(x * 0.70710678118654752f));
}

// MODE 0: out[row*N+col] = A@W + bias                       (qkv)
// MODE 1: t=win_to_tok(row); out[t*N+col] = A@W+bias+res[t*N+col]  (proj+resid, unpartition)
// MODE 2: out[row*N+col] = gelu(A@W + bias)                 (fc1)
// MODE 3: out[row*N+col] = A@W + bias + res[row*N+col]      (fc2+resid)
// BM=BN=128, BK=16, 256 threads, 8x8 micro-tile. All dims assumed divisible.
template<int MODE>
__global__ __launch_bounds__(256) void gemm_kernel(
    const float* __restrict__ A, const float* __restrict__ W,
    const float* __restrict__ bias, const float* __restrict__ res,
    float* __restrict__ out, int N, int K)
{
  __shared__ float As[16][132];
  __shared__ float Bs[16][132];
  const int tid = threadIdx.x;
  const int bm = blockIdx.y * 128, bn = blockIdx.x * 128;
  const int tx = tid & 15, ty = tid >> 4;
  float acc[8][8] = {};

  const int ar0 = tid >> 2, akq = (tid & 3) << 2;       // A stage: rows 0..63 / 64..127
  const int br0 = tid >> 5, bc  = (tid & 31) << 2;      // B stage: rows 0..7 / 8..15

  for (int kt = 0; kt < K; kt += 16) {
    float4 a0 = *(const float4*)(A + (size_t)(bm + ar0) * K + kt + akq);
    float4 a1 = *(const float4*)(A + (size_t)(bm + ar0 + 64) * K + kt + akq);
    float4 b0 = *(const float4*)(W + (size_t)(kt + br0) * N + bn + bc);
    float4 b1 = *(const float4*)(W + (size_t)(kt + br0 + 8) * N + bn + bc);
    __syncthreads();
    As[akq + 0][ar0] = a0.x; As[akq + 1][ar0] = a0.y;
    As[akq + 2][ar0] = a0.z; As[akq + 3][ar0] = a0.w;
    As[akq + 0][ar0 + 64] = a1.x; As[akq + 1][ar0 + 64] = a1.y;
    As[akq + 2][ar0 + 64] = a1.z; As[akq + 3][ar0 + 64] = a1.w;
    *(float4*)&Bs[br0][bc]     = b0;
    *(float4*)&Bs[br0 + 8][bc] = b1;
    __syncthreads();
#pragma unroll
    for (int kk = 0; kk < 16; kk++) {
      float4 am0 = *(const float4*)&As[kk][ty * 8];
      float4 am1 = *(const float4*)&As[kk][ty * 8 + 4];
      float4 bv0 = *(const float4*)&Bs[kk][tx * 8];
      float4 bv1 = *(const float4*)&Bs[kk][tx * 8 + 4];
      float am[8] = {am0.x, am0.y, am0.z, am0.w, am1.x, am1.y, am1.z, am1.w};
      float bv[8] = {bv0.x, bv0.y, bv0.z, bv0.w, bv1.x, bv1.y, bv1.z, bv1.w};
#pragma unroll
      for (int i = 0; i < 8; i++)
#pragma unroll
        for (int j = 0; j < 8; j++)
          acc[i][j] = fmaf(am[i], bv[j], acc[i][j]);
    }
  }

  const int col = bn + tx * 8;
  float bias8[8];
#pragma unroll
  for (int j = 0; j < 8; j++) bias8[j] = bias[col + j];

#pragma unroll
  for (int i = 0; i < 8; i++) {
    int row = bm + ty * 8 + i;
    float v[8];
#pragma unroll
    for (int j = 0; j < 8; j++) v[j] = acc[i][j] + bias8[j];
    if (MODE == 0) {
      float* op = out + (size_t)row * N + col;
#pragma unroll
      for (int j = 0; j < 8; j++) op[j] = v[j];
    } else if (MODE == 1) {
      int t_ = win_to_tok(row);
      const float* rp = res + (size_t)t_ * N + col;
      float* op = out + (size_t)t_ * N + col;
#pragma unroll
      for (int j = 0; j < 8; j++) op[j] = v[j] + rp[j];
    } else if (MODE == 2) {
      float* op = out + (size_t)row * N + col;
#pragma unroll
      for (int j = 0; j < 8; j++) op[j] = gelu_f(v[j]);
    } else {
      const float* rp = res + (size_t)row * N + col;
      float* op = out + (size_t)row * N + col;
#pragma unroll
      for (int j = 0; j < 8; j++) op[j] = v[j] + rp[j];
    }
  }
}

// ---------------------------------------------------------------- Attention
// One block per (window, head). Thread = one q row (196 active of 256).
// q kept in registers; K/V rows are wave-uniform addresses (scalarizable).
// Decomposed rel-pos: s = SCALE*q.k + dot(q,Rh[qh-kh+13]) + dot(q,Rw[qw-kw+13])
// rel_w table per-thread in LDS (stride 15 -> conflict-free); rel_h recomputed
// per outer kh iteration (scalar). Single-pass online softmax.
__global__ __launch_bounds__(256) void attn_kernel(
    const float* __restrict__ qkv,
    const float* __restrict__ relh, const float* __restrict__ relw,
    float* __restrict__ out)
{
  __shared__ float rwbuf[L][15];
  const int n = blockIdx.x / HEADS;
  const int h = blockIdx.x % HEADS;
  const int r = threadIdx.x;
  if (r >= L) return;
  const int qh = r / WIN, qw = r % WIN;

  const float* qrow = qkv + (size_t)(n * L + r) * NQKV + h * HD;
  float4 q4[16];
#pragma unroll
  for (int i = 0; i < 16; i++) q4[i] = ((const float4*)qrow)[i];

  for (int kw = 0; kw < WIN; kw++) {
    const float4* rp = (const float4*)(relw + (size_t)(qw - kw + WIN - 1) * HD);
    float s0 = 0, s1 = 0, s2 = 0, s3 = 0;
#pragma unroll
    for (int i = 0; i < 16; i++) {
      float4 t = rp[i];
      s0 = fmaf(q4[i].x, t.x, s0); s1 = fmaf(q4[i].y, t.y, s1);
      s2 = fmaf(q4[i].z, t.z, s2); s3 = fmaf(q4[i].w, t.w, s3);
    }
    rwbuf[r][kw] = (s0 + s1) + (s2 + s3);
  }

  float m = -INFINITY, l = 0.0f;
  float4 o4[16];
#pragma unroll
  for (int i = 0; i < 16; i++) o4[i] = make_float4(0.f, 0.f, 0.f, 0.f);

  for (int kh = 0; kh < WIN; kh++) {
    const float4* hp = (const float4*)(relh + (size_t)(qh - kh + WIN - 1) * HD);
    float h0 = 0, h1 = 0, h2 = 0, h3 = 0;
#pragma unroll
    for (int i = 0; i < 16; i++) {
      float4 t = hp[i];
      h0 = fmaf(q4[i].x, t.x, h0); h1 = fmaf(q4[i].y, t.y, h1);
      h2 = fmaf(q4[i].z, t.z, h2); h3 = fmaf(q4[i].w, t.w, h3);
    }
    const float rhv = (h0 + h1) + (h2 + h3);
    const float* kbase = qkv + (size_t)(n * L + kh * WIN) * NQKV + C + h * HD;
    const float* vbase = kbase + C;
    for (int kw = 0; kw < WIN; kw++) {
      const float4* kr = (const float4*)(kbase + (size_t)kw * NQKV);
      float s0 = 0, s1 = 0, s2 = 0, s3 = 0;
#pragma unroll
      for (int i = 0; i < 16; i++) {
        float4 t = kr[i];
        s0 = fmaf(q4[i].x, t.x, s0); s1 = fmaf(q4[i].y, t.y, s1);
        s2 = fmaf(q4[i].z, t.z, s2); s3 = fmaf(q4[i].w, t.w, s3);
      }
      float s = ((s0 + s1) + (s2 + s3)) * SCALEF + rhv + rwbuf[r][kw];
      float mn = fmaxf(m, s);
      float al = __expf(m - mn);
      float p  = __expf(s - mn);
      l = l * al + p;
      const float4* vr = (const float4*)(vbase + (size_t)kw * NQKV);
#pragma unroll
      for (int i = 0; i < 16; i++) {
        float4 vv = vr[i];
        o4[i].x = fmaf(p, vv.x, o4[i].x * al);
        o4[i].y = fmaf(p, vv.y, o4[i].y * al);
        o4[i].z = fmaf(p, vv.z, o4[i].z * al);
        o4[i].w = fmaf(p, vv.w, o4[i].w * al);
      }
      m = mn;
    }
  }
  const float inv = 1.0f / l;
  float* orow = out + (size_t)(n * L + r) * C + h * HD;
#pragma unroll
  for (int i = 0; i < 16; i++) {
    float4 v = o4[i];
    ((float4*)orow)[i] = make_float4(v.x * inv, v.y * inv, v.z * inv, v.w * inv);
  }
}

// ---------------------------------------------------------------- launch
extern "C" void kernel_launch(void* const* d_in, const int* in_sizes, int n_in,
                              void* d_out, int out_size, void* d_ws, size_t ws_size,
                              hipStream_t stream)
{
  const float* x      = (const float*)d_in[0];
  const float* qkv_w  = (const float*)d_in[1];
  const float* qkv_b  = (const float*)d_in[2];
  const float* proj_w = (const float*)d_in[3];
  const float* proj_b = (const float*)d_in[4];
  const float* rel_h  = (const float*)d_in[5];
  const float* rel_w  = (const float*)d_in[6];
  const float* n1w    = (const float*)d_in[7];
  const float* n1b    = (const float*)d_in[8];
  const float* n2w    = (const float*)d_in[9];
  const float* n2b    = (const float*)d_in[10];
  const float* fc1_w  = (const float*)d_in[11];
  const float* fc1_b  = (const float*)d_in[12];
  const float* fc2_w  = (const float*)d_in[13];
  const float* fc2_b  = (const float*)d_in[14];
  float* outp = (float*)d_out;

  // workspace layout (floats): R0 = M*384, R1 = M*1152. Total = M*1536*4B ~= 662 MiB
  float* R0  = (float*)d_ws;                  // xw -> attn_out -> h1 chunks
  float* R1  = R0 + (size_t)TOKENS * C;       // qkv -> x2 | xn2
  float* x2  = R1;
  float* xn2 = R1 + (size_t)TOKENS * C;

  // 1. LN1 + window partition
  ln_kernel<true><<<TOKENS, 128, 0, stream>>>(x, n1w, n1b, R0);
  // 2. qkv = xw @ qkv_w + b    [M,384]x[384,1152]
  gemm_kernel<0><<<dim3(NQKV / 128, TOKENS / 128), 256, 0, stream>>>(
      R0, qkv_w, qkv_b, nullptr, R1, NQKV, C);
  // 3. attention -> attn_out (windowed rows) in R0
  attn_kernel<<<576 * HEADS, 256, 0, stream>>>(R1, rel_h, rel_w, R0);
  // 4. x2 = x + attn_out @ proj_w + b   (unpartition via row remap)
  gemm_kernel<1><<<dim3(C / 128, TOKENS / 128), 256, 0, stream>>>(
      R0, proj_w, proj_b, x, x2, C, C);
  // 5. LN2
  ln_kernel<false><<<TOKENS, 128, 0, stream>>>(x2, n2w, n2b, xn2);
  // 6. MLP in 6 row-chunks (h1 chunk reuses R0)
  const int CH = TOKENS / 6;  // 18816 rows, 147 tiles of 128
  for (int c = 0; c < 6; c++) {
    size_t ro = (size_t)c * CH;
    gemm_kernel<2><<<dim3(NFC / 128, CH / 128), 256, 0, stream>>>(
        xn2 + ro * C, fc1_w, fc1_b, nullptr, R0, NFC, C);
    gemm_kernel<3><<<dim3(C / 128, CH / 128), 256, 0, stream>>>(
        R0, fc2_w, fc2_b, x2 + ro * C, outp + ro * C, C, NFC);
  }
}

// Round 2
// 4836.497 us; speedup vs baseline: 1.5537x; 1.5537x over previous
//
#include <hip/hip_runtime.h>
#include <math.h>

#define TOKENS 112896
#define C      384
#define NQKV   1152
#define NFC    1536
#define HEADS  6
#define HD     64
#define WIN    14
#define L      196
#define NWS    24
#define SCALEF 0.125f
#define CHUNK  49

typedef unsigned int  u32;
typedef unsigned short u16;
typedef short short8 __attribute__((ext_vector_type(8)));
typedef float floatx4 __attribute__((ext_vector_type(4)));

__device__ __forceinline__ u16 f2bf(float f) {
  u32 u = __float_as_uint(f);
  u += 0x7FFFu + ((u >> 16) & 1u);   // RNE (finite values only here)
  return (u16)(u >> 16);
}

// async 16B global->LDS copy; lds base must be wave-uniform, HW adds lane*16
__device__ __forceinline__ void async16(u16* lds, const u16* g) {
  __builtin_amdgcn_global_load_lds((const __attribute__((address_space(1))) void*)g,
                                   (__attribute__((address_space(3))) void*)lds,
                                   16, 0, 0);
}

__device__ __forceinline__ int win_to_tok(int r) {
  int n = r / L, l = r % L;
  int wh = n / NWS, ww = n % NWS;
  int ih = l / WIN, iw = l % WIN;
  return (wh * WIN + ih) * 336 + ww * WIN + iw;
}

// ---------------------------------------------------------------- weight T+cvt
// out[n*K+k] = bf16(in[k*N+n]); grid covers K*N output elements
__global__ __launch_bounds__(256) void conv_t_kernel(const float* __restrict__ in,
    u16* __restrict__ out, int K, int N)
{
  int idx = blockIdx.x * 256 + threadIdx.x;
  if (idx >= K * N) return;
  int n = idx / K, k = idx % K;
  out[idx] = f2bf(in[(size_t)k * N + n]);
}

// ---------------------------------------------------------------- LayerNorm
template<bool PERMUTE>
__global__ __launch_bounds__(128) void ln_kernel(const float* __restrict__ x,
    const float* __restrict__ w, const float* __restrict__ b,
    u16* __restrict__ out)
{
  const int t = blockIdx.x;
  const int tid = threadIdx.x;
  const float* xr = x + (size_t)t * C;
  float v0 = xr[tid], v1 = xr[tid + 128], v2 = xr[tid + 256];
  float s  = v0 + v1 + v2;
  float ss = v0 * v0 + v1 * v1 + v2 * v2;
#pragma unroll
  for (int off = 32; off > 0; off >>= 1) {
    s  += __shfl_down(s, off);
    ss += __shfl_down(ss, off);
  }
  __shared__ float red[4];
  if ((tid & 63) == 0) { red[(tid >> 6) * 2 + 0] = s; red[(tid >> 6) * 2 + 1] = ss; }
  __syncthreads();
  float S  = red[0] + red[2];
  float SS = red[1] + red[3];
  float mean = S * (1.0f / C);
  float var  = SS * (1.0f / C) - mean * mean;
  float rstd = rsqrtf(var + 1e-5f);
  size_t orow;
  if (PERMUTE) {
    int h_ = t / 336, w_ = t % 336;
    int wh = h_ / WIN, ih = h_ % WIN;
    int ww = w_ / WIN, iw = w_ % WIN;
    orow = (size_t)((wh * NWS + ww) * L + ih * WIN + iw);
  } else {
    orow = (size_t)t;
  }
  u16* op = out + orow * C;
  op[tid]       = f2bf((v0 - mean) * rstd * w[tid]       + b[tid]);
  op[tid + 128] = f2bf((v1 - mean) * rstd * w[tid + 128] + b[tid + 128]);
  op[tid + 256] = f2bf((v2 - mean) * rstd * w[tid + 256] + b[tid + 256]);
}

// ---------------------------------------------------------------- bf16 MFMA GEMM
// A[M,K] bf16 row-major, Bt[N,K] bf16 row-major (pre-transposed weight).
// 128x128 tile, BK=32, 256 threads = 4 waves in 2x2, each wave 4x4 16x16 tiles.
// MODE 0: out(bf16)[row*N+col] = v                        (qkv)
// MODE 1: t=win_to_tok(row); out(f32)[t*N+c] = v + res    (proj + resid, unpartition)
// MODE 2: out(bf16) = gelu(v)                             (fc1)
// MODE 3: out(f32)[row*N+c] = v + res                     (fc2 + resid)
template<int MODE>
__global__ __launch_bounds__(256) void gemm_bf16(
    const u16* __restrict__ A, const u16* __restrict__ Bt,
    const float* __restrict__ bias, const float* __restrict__ res,
    void* __restrict__ outv, int N, int K)
{
  __shared__ u16 As[128 * 32];
  __shared__ u16 Bs[128 * 32];
  const int tid = threadIdx.x;
  const int w = tid >> 6, l = tid & 63;
  const int bm = blockIdx.y * 128, bn = blockIdx.x * 128;
  const int wm = (w >> 1) * 64, wn = (w & 1) * 64;
  const int lm = l & 15, quad = l >> 4;

  floatx4 acc[4][4] = {};

  // staging: thread t covers row t>>2 (and +64), 16B segment t&3
  const int srow = tid >> 2, sseg = tid & 3;
  const u16* Ag0 = A  + (size_t)(bm + srow)      * K + sseg * 8;
  const u16* Ag1 = A  + (size_t)(bm + srow + 64) * K + sseg * 8;
  const u16* Bg0 = Bt + (size_t)(bn + srow)      * K + sseg * 8;
  const u16* Bg1 = Bt + (size_t)(bn + srow + 64) * K + sseg * 8;
  u16* Asw0 = As + w * 512;          // wave-uniform LDS bases (bytes: w*1024)
  u16* Asw1 = As + 2048 + w * 512;
  u16* Bsw0 = Bs + w * 512;
  u16* Bsw1 = Bs + 2048 + w * 512;

  for (int kt = 0; kt < K; kt += 32) {
    async16(Asw0, Ag0 + kt);
    async16(Asw1, Ag1 + kt);
    async16(Bsw0, Bg0 + kt);
    async16(Bsw1, Bg1 + kt);
    __syncthreads();   // vmcnt(0) drained by compiler before barrier
    short8 af[4], bf[4];
#pragma unroll
    for (int i = 0; i < 4; i++)
      af[i] = *(const short8*)(As + (wm + i * 16 + lm) * 32 + quad * 8);
#pragma unroll
    for (int j = 0; j < 4; j++)
      bf[j] = *(const short8*)(Bs + (wn + j * 16 + lm) * 32 + quad * 8);
#pragma unroll
    for (int i = 0; i < 4; i++)
#pragma unroll
      for (int j = 0; j < 4; j++)
        acc[i][j] = __builtin_amdgcn_mfma_f32_16x16x32_bf16(af[i], bf[j], acc[i][j], 0, 0, 0);
    __syncthreads();   // all waves done reading before next stage overwrites
  }

  // epilogue; C/D layout: col = lane&15, row = quad*4 + reg
  const int colbase = bn + wn + lm;
  float bb[4];
#pragma unroll
  for (int j = 0; j < 4; j++) bb[j] = bias[colbase + j * 16];

#pragma unroll
  for (int i = 0; i < 4; i++) {
#pragma unroll
    for (int reg = 0; reg < 4; reg++) {
      int row = bm + wm + i * 16 + quad * 4 + reg;
      size_t ro;
      if (MODE == 1) ro = (size_t)win_to_tok(row) * N;
      else           ro = (size_t)row * N;
#pragma unroll
      for (int j = 0; j < 4; j++) {
        float v = acc[i][j][reg] + bb[j];
        int col = colbase + j * 16;
        if (MODE == 0) {
          ((u16*)outv)[ro + col] = f2bf(v);
        } else if (MODE == 1) {
          ((float*)outv)[ro + col] = v + res[ro + col];
        } else if (MODE == 2) {
          ((u16*)outv)[ro + col] = f2bf(0.5f * v * (1.0f + erff(v * 0.70710678118654752f)));
        } else {
          ((float*)outv)[ro + col] = v + res[ro + col];
        }
      }
    }
  }
}

// ---------------------------------------------------------------- Attention
// One block per (window, head). Thread = q row (196 of 256 active).
// K/V staged to LDS fp32 in chunks of 49 rows; rel_h/rel_w dots precomputed
// into stride-15 LDS. No max-subtraction (logits O(1), exp cannot overflow)
// -> PV is a single fma per element, no serial rescale chain.
__global__ __launch_bounds__(256) void attn_kernel(
    const u16* __restrict__ qkv,
    const float* __restrict__ relh, const float* __restrict__ relw,
    u16* __restrict__ out)
{
  __shared__ float Kbuf[CHUNK][64];
  __shared__ float Vbuf[CHUNK][64];
  __shared__ float rhbuf[L][15];
  __shared__ float rwbuf[L][15];
  const int n = blockIdx.x / HEADS;
  const int h = blockIdx.x % HEADS;
  const int tid = threadIdx.x;
  const bool active = (tid < L);

  float qf[64];
  float4 o4[16];
  float lsum = 0.0f;
#pragma unroll
  for (int i = 0; i < 16; i++) o4[i] = make_float4(0.f, 0.f, 0.f, 0.f);

  if (active) {
    const int qh = tid / WIN, qw = tid % WIN;
    const u16* qrow = qkv + (size_t)(n * L + tid) * NQKV + h * HD;
#pragma unroll
    for (int g = 0; g < 8; g++) {
      uint4 u = *(const uint4*)(qrow + 8 * g);
      u32 wd[4] = {u.x, u.y, u.z, u.w};
#pragma unroll
      for (int j = 0; j < 4; j++) {
        qf[8 * g + 2 * j]     = __uint_as_float(wd[j] << 16);
        qf[8 * g + 2 * j + 1] = __uint_as_float(wd[j] & 0xFFFF0000u);
      }
    }
    for (int k = 0; k < WIN; k++) {
      const float* hp = relh + (size_t)(qh - k + WIN - 1) * HD;
      const float* wp = relw + (size_t)(qw - k + WIN - 1) * HD;
      float sh = 0.f, sw = 0.f;
#pragma unroll
      for (int i = 0; i < 64; i++) { sh = fmaf(qf[i], hp[i], sh); sw = fmaf(qf[i], wp[i], sw); }
      rhbuf[tid][k] = sh;
      rwbuf[tid][k] = sw;
    }
  }

  for (int kc = 0; kc < L; kc += CHUNK) {
    __syncthreads();
    for (int idx = tid; idx < CHUNK * 8; idx += 256) {
      int row = idx >> 3, seg = idx & 7;
      const u16* kp = qkv + (size_t)(n * L + kc + row) * NQKV + C + h * HD + seg * 8;
      const u16* vp = kp + C;
      uint4 ku = *(const uint4*)kp;
      uint4 vu = *(const uint4*)vp;
      u32 kw_[4] = {ku.x, ku.y, ku.z, ku.w};
      u32 vw_[4] = {vu.x, vu.y, vu.z, vu.w};
      float kf[8], vf[8];
#pragma unroll
      for (int j = 0; j < 4; j++) {
        kf[2 * j]     = __uint_as_float(kw_[j] << 16);
        kf[2 * j + 1] = __uint_as_float(kw_[j] & 0xFFFF0000u);
        vf[2 * j]     = __uint_as_float(vw_[j] << 16);
        vf[2 * j + 1] = __uint_as_float(vw_[j] & 0xFFFF0000u);
      }
      *(float4*)&Kbuf[row][seg * 8]     = make_float4(kf[0], kf[1], kf[2], kf[3]);
      *(float4*)&Kbuf[row][seg * 8 + 4] = make_float4(kf[4], kf[5], kf[6], kf[7]);
      *(float4*)&Vbuf[row][seg * 8]     = make_float4(vf[0], vf[1], vf[2], vf[3]);
      *(float4*)&Vbuf[row][seg * 8 + 4] = make_float4(vf[4], vf[5], vf[6], vf[7]);
    }
    __syncthreads();
    if (active) {
      for (int kk = 0; kk < CHUNK; kk++) {
        int k = kc + kk;
        int kh = k / WIN, kw2 = k % WIN;   // wave-uniform scalars
        const float4* kr4 = (const float4*)&Kbuf[kk][0];
        float s0 = 0.f, s1 = 0.f, s2 = 0.f, s3 = 0.f;
#pragma unroll
        for (int i = 0; i < 16; i++) {
          float4 t = kr4[i];
          s0 = fmaf(qf[4 * i + 0], t.x, s0); s1 = fmaf(qf[4 * i + 1], t.y, s1);
          s2 = fmaf(qf[4 * i + 2], t.z, s2); s3 = fmaf(qf[4 * i + 3], t.w, s3);
        }
        float s = ((s0 + s1) + (s2 + s3)) * SCALEF + rhbuf[tid][kh] + rwbuf[tid][kw2];
        float p = __expf(s);
        lsum += p;
        const float4* vr4 = (const float4*)&Vbuf[kk][0];
#pragma unroll
        for (int i = 0; i < 16; i++) {
          float4 t = vr4[i];
          o4[i].x = fmaf(p, t.x, o4[i].x); o4[i].y = fmaf(p, t.y, o4[i].y);
          o4[i].z = fmaf(p, t.z, o4[i].z); o4[i].w = fmaf(p, t.w, o4[i].w);
        }
      }
    }
  }

  if (active) {
    float inv = 1.0f / lsum;
    u16* orow = out + (size_t)(n * L + tid) * C + h * HD;
#pragma unroll
    for (int i = 0; i < 16; i += 2) {
      uint4 u;
      u.x = (u32)f2bf(o4[i].x * inv)     | ((u32)f2bf(o4[i].y * inv) << 16);
      u.y = (u32)f2bf(o4[i].z * inv)     | ((u32)f2bf(o4[i].w * inv) << 16);
      u.z = (u32)f2bf(o4[i + 1].x * inv) | ((u32)f2bf(o4[i + 1].y * inv) << 16);
      u.w = (u32)f2bf(o4[i + 1].z * inv) | ((u32)f2bf(o4[i + 1].w * inv) << 16);
      *(uint4*)(orow + 4 * i) = u;
    }
  }
}

// ---------------------------------------------------------------- launch
extern "C" void kernel_launch(void* const* d_in, const int* in_sizes, int n_in,
                              void* d_out, int out_size, void* d_ws, size_t ws_size,
                              hipStream_t stream)
{
  const float* x      = (const float*)d_in[0];
  const float* qkv_w  = (const float*)d_in[1];
  const float* qkv_b  = (const float*)d_in[2];
  const float* proj_w = (const float*)d_in[3];
  const float* proj_b = (const float*)d_in[4];
  const float* rel_h  = (const float*)d_in[5];
  const float* rel_w  = (const float*)d_in[6];
  const float* n1w    = (const float*)d_in[7];
  const float* n1b    = (const float*)d_in[8];
  const float* n2w    = (const float*)d_in[9];
  const float* n2b    = (const float*)d_in[10];
  const float* fc1_w  = (const float*)d_in[11];
  const float* fc1_b  = (const float*)d_in[12];
  const float* fc2_w  = (const float*)d_in[13];
  const float* fc2_b  = (const float*)d_in[14];

  // workspace: [W0: M*384 bf16][W1: M*1536 bf16][W2: M*384 f32][WT: weights bf16]
  // = 86.7MB + 346.8MB + 173.4MB + 3.5MB = 610.5 MB (round-1 proved >=693MB available)
  u16*  W0 = (u16*)d_ws;                                             // xw -> attn_out -> xn2
  u16*  W1 = (u16*)((char*)d_ws + 86704128);                         // qkv -> h1
  float* W2 = (float*)((char*)d_ws + 86704128 + 346816512);          // x2
  u16*  WT = (u16*)((char*)d_ws + 86704128 + 346816512 + 173408256);
  u16* qkv_wT  = WT;                   // [1152,384]
  u16* proj_wT = qkv_wT + 442368;      // [384,384]
  u16* fc1_wT  = proj_wT + 147456;     // [1536,384]
  u16* fc2_wT  = fc1_wT + 589824;      // [384,1536]

  conv_t_kernel<<<(442368 + 255) / 256, 256, 0, stream>>>(qkv_w, qkv_wT, C, NQKV);
  conv_t_kernel<<<(147456 + 255) / 256, 256, 0, stream>>>(proj_w, proj_wT, C, C);
  conv_t_kernel<<<(589824 + 255) / 256, 256, 0, stream>>>(fc1_w, fc1_wT, C, NFC);
  conv_t_kernel<<<(589824 + 255) / 256, 256, 0, stream>>>(fc2_w, fc2_wT, NFC, C);

  // 1. LN1 + window partition -> bf16
  ln_kernel<true><<<TOKENS, 128, 0, stream>>>(x, n1w, n1b, W0);
  // 2. qkv = xw @ qkv_w + b  -> bf16 [M,1152]
  gemm_bf16<0><<<dim3(NQKV / 128, TOKENS / 128), 256, 0, stream>>>(
      W0, qkv_wT, qkv_b, nullptr, W1, NQKV, C);
  // 3. attention -> attn_out bf16 (windowed rows) in W0
  attn_kernel<<<576 * HEADS, 256, 0, stream>>>(W1, rel_h, rel_w, W0);
  // 4. x2 = x + attn_out @ proj_w + b (unpartition remap) -> f32
  gemm_bf16<1><<<dim3(C / 128, TOKENS / 128), 256, 0, stream>>>(
      W0, proj_wT, proj_b, x, W2, C, C);
  // 5. LN2 -> bf16
  ln_kernel<false><<<TOKENS, 128, 0, stream>>>(W2, n2w, n2b, W0);
  // 6. h1 = gelu(xn2 @ fc1_w + b) -> bf16 [M,1536]
  gemm_bf16<2><<<dim3(NFC / 128, TOKENS / 128), 256, 0, stream>>>(
      W0, fc1_wT, fc1_b, nullptr, W1, NFC, C);
  // 7. out = x2 + h1 @ fc2_w + b -> f32
  gemm_bf16<3><<<dim3(C / 128, TOKENS / 128), 256, 0, stream>>>(
      W1, fc2_wT, fc2_b, W2, (float*)d_out, C, NFC);
}